// Round 1
// baseline (176.971 us; speedup 1.0000x reference)
//
#include <hip/hip_runtime.h>
#include <math.h>

// Problem constants (b=8, c=2048, e=64, h=8)
#define NTOK 16384
#define EDIM 64
#define HHE  512   // h*e
#define TOKPAD 260 // half2 slots per token row: 256 + 4 pad (16B-aligned rows)

typedef _Float16 half8 __attribute__((ext_vector_type(8)));   // MFMA operand type
typedef __fp16   half2v __attribute__((ext_vector_type(2)));  // builtin V2h type
typedef float    floatx4 __attribute__((ext_vector_type(4)));
typedef float    float2v __attribute__((ext_vector_type(2))); // packed-fp32 pair

__device__ __forceinline__ half8 cvt8(const float4 a, const float4 b) {
    half8 h;
    h[0] = (_Float16)a.x; h[1] = (_Float16)a.y;
    h[2] = (_Float16)a.z; h[3] = (_Float16)a.w;
    h[4] = (_Float16)b.x; h[5] = (_Float16)b.y;
    h[6] = (_Float16)b.z; h[7] = (_Float16)b.w;
    return h;
}

// fp32 += half2 . half2 (v_dot2_f32_f16); float fallback if builtin missing
__device__ __forceinline__ float dot2(half2v a, half2v b, float c) {
#if __has_builtin(__builtin_amdgcn_fdot2)
    return __builtin_amdgcn_fdot2(a, b, c, false);
#else
    return fmaf((float)a[0], (float)b[0], fmaf((float)a[1], (float)b[1], c));
#endif
}
__device__ __forceinline__ half2v pk(float x, float y) {
    return __builtin_amdgcn_cvt_pkrtz(x, y);   // v_cvt_pkrtz_f16_f32 (V2h)
}
union h2u { half2v h; unsigned int u; };

// ---- packed fp32 (VOP3P, full-rate since gfx90a; hipcc won't auto-form) ----
__device__ __forceinline__ float2v pk_add(float2v a, float2v b) {
    float2v d;
    asm("v_pk_add_f32 %0, %1, %2" : "=v"(d) : "v"(a), "v"(b));
    return d;
}
__device__ __forceinline__ float2v pk_mul(float2v a, float2v b) {
    float2v d;
    asm("v_pk_mul_f32 %0, %1, %2" : "=v"(d) : "v"(a), "v"(b));
    return d;
}
__device__ __forceinline__ float2v pk_fma(float2v a, float2v b, float2v c) {
    float2v d;
    asm("v_pk_fma_f32 %0, %1, %2, %3" : "=v"(d) : "v"(a), "v"(b), "v"(c));
    return d;
}

__device__ __forceinline__ float pgen(float z, float inv) {
    return z > 0.0f ? exp2f(inv * log2f(fmaxf(z, 1e-30f))) : 0.0f;
}

// ---------------------------------------------------------------------------
// Kernel 0: fp32 -> fp16 (RTN cast) for the 4 weight matrices only.
// Wq is pre-scaled by (alpha-1)/sqrt(e) = am1*0.125 so the score scale
// vanishes from the consumer hot loop. x is converted inline in kernel 1.
// All 4 matrices are 32768 elems -> grid (16,4), no bounds check needed.
// ---------------------------------------------------------------------------
__global__ __launch_bounds__(256) void cvt_fp16_kernel(
    const float* __restrict__ Wk, const float* __restrict__ Wq,
    const float* __restrict__ Wv, const float* __restrict__ Wu,
    __fp16* __restrict__ wkh, __fp16* __restrict__ wqh,
    __fp16* __restrict__ wvh, __fp16* __restrict__ wuh,
    const float* alpha_p)
{
    const int z = blockIdx.y;
    const float* src; __fp16* dst;
    float s = 1.0f;
    if      (z == 0) { src = Wk; dst = wkh; }
    else if (z == 1) { src = Wq; dst = wqh; s = (alpha_p[0] - 1.0f) * 0.125f; }
    else if (z == 2) { src = Wv; dst = wvh; }
    else             { src = Wu; dst = wuh; }
    const int idx = (blockIdx.x * 256 + threadIdx.x) * 8;
    float4 a = *(const float4*)(src + idx);
    float4 b = *(const float4*)(src + idx + 4);
    a.x *= s; a.y *= s; a.z *= s; a.w *= s;
    b.x *= s; b.y *= s; b.z *= s; b.w *= s;
    *(half8*)(dst + idx) = cvt8(a, b);
}

// ---------------------------------------------------------------------------
// Kernel 1: FULLY FUSED qkv + entmax-attention + output projection.
// Block = 16 tokens, 4 waves. R19: packed-fp32 (v_pk_*_f32) entmax inner
// loops (2 insts/elem instead of 3 on the 9 f-eval passes), score scale
// folded into Wq/bq, x converted inline (bitwise-identical RTN cast).
// res overlay of qT + out MFMA unchanged from R18.
// ---------------------------------------------------------------------------
__global__ __launch_bounds__(256) void qkv_attn_out_kernel(
    const float* __restrict__ x,
    const __fp16* __restrict__ wkh, const float* __restrict__ bk,
    const __fp16* __restrict__ wqh, const float* __restrict__ bq,
    const __fp16* __restrict__ wvh, const float* __restrict__ bv,
    const __fp16* __restrict__ wuh, const float* __restrict__ bu,
    float* __restrict__ out, const float* alpha_p)
{
    __shared__ __align__(16) half2v qT[16 * TOKPAD];  // [tok][i*4+hpair] -> res overlay
    __shared__ __align__(16) half2v kT[16 * TOKPAD];  // [tok][j*4 + hpair]
    __shared__ __align__(16) half2v vT[16 * TOKPAD];  // [tok][h*32 + jpair]

    const int tid  = threadIdx.x;
    const int lane = tid & 63;
    const int w    = tid >> 6;
    const int tok0 = blockIdx.x * 16;

    const int m    = lane & 15;            // token (B row)
    const int quad = lane >> 4;

    const float alpha = alpha_p[0];
    const float am1   = alpha - 1.0f;
    const float s_q   = am1 * 0.125f;      // matches cvt kernel's Wq scale

    // ---- x B-fragments: fp32 load + RTN cast (identical to old cvt path)
    const float* xrow = x + (size_t)(tok0 + m) * EDIM + quad * 8;
    half8 bfr[2];
    {
        const float4 a0 = *(const float4*)(xrow);
        const float4 a1 = *(const float4*)(xrow + 4);
        const float4 a2 = *(const float4*)(xrow + 32);
        const float4 a3 = *(const float4*)(xrow + 36);
        bfr[0] = cvt8(a0, a1);
        bfr[1] = cvt8(a2, a3);
    }

    // ---- producer: units w*3 .. w*3+2; unit = z*4 + ntile
    #pragma unroll
    for (int uu = 0; uu < 3; ++uu) {
        const int unit = w * 3 + uu;
        const int z    = unit >> 2;            // 0=k, 1=q, 2=v
        const int col0 = (unit & 3) * 128;
        const __fp16* W   = (z == 0) ? wkh : (z == 1) ? wqh : wvh;
        const float* bias = (z == 0) ? bk : (z == 1) ? bq : bv;
        half2v* dstT      = (z == 0) ? kT : (z == 1) ? qT : vT;
        // q path: W pre-scaled; bias scaled here via exact fmaf (bs=1 for k)
        const float bs    = (z == 1) ? s_q : 1.0f;

        #pragma unroll
        for (int ct = 0; ct < 8; ++ct) {
            const int n = col0 + ct * 16 + m;
            // permuted W row for q/k; natural for v
            const int grow = (z < 2) ? ((n & 7) * 64 + (n >> 3)) : n;
            const __fp16* wrow = W + (size_t)grow * EDIM + quad * 8;
            floatx4 acc = (floatx4){0.f, 0.f, 0.f, 0.f};
            #pragma unroll
            for (int kc = 0; kc < 2; ++kc) {
                const half8 af = *(const half8*)(wrow + kc * 32);  // direct fp16
                acc = __builtin_amdgcn_mfma_f32_16x16x32_f16(af, bfr[kc], acc, 0, 0, 0);
            }
            // lane's 4 regs = D rows quad*4+0..3, D col = m (token)
            h2u p0, p1;
            if (z < 2) {
                // output rows g(n'): h = 4*(quad&1)+reg, j = col0/8+ct*2+(quad>>1)
                const int hbase = 4 * (quad & 1);
                const int j     = (col0 >> 3) + ct * 2 + (quad >> 1);
                float o0 = fmaf(bias[(hbase + 0) * 64 + j], bs, acc[0]);
                float o1 = fmaf(bias[(hbase + 1) * 64 + j], bs, acc[1]);
                float o2 = fmaf(bias[(hbase + 2) * 64 + j], bs, acc[2]);
                float o3 = fmaf(bias[(hbase + 3) * 64 + j], bs, acc[3]);
                p0.h = pk(o0, o1);                 // h-pair 2*(quad&1)
                p1.h = pk(o2, o3);                 // h-pair 2*(quad&1)+1
                uint2 st; st.x = p0.u; st.y = p1.u;
                *(uint2*)&dstT[m * TOKPAD + j * 4 + 2 * (quad & 1)] = st;
            } else {
                // natural: cols nn..nn+3 = v[h][jj..jj+3]
                const int nn = col0 + ct * 16 + quad * 4;
                const int h  = nn >> 6;
                const int jj = nn & 63;
                const float4 b4 = *(const float4*)&bias[nn];
                p0.h = pk(acc[0] + b4.x, acc[1] + b4.y);
                p1.h = pk(acc[2] + b4.z, acc[3] + b4.w);
                uint2 st; st.x = p0.u; st.y = p1.u;
                *(uint2*)&dstT[m * TOKPAD + h * 32 + (jj >> 1)] = st;
            }
        }
    }
    __syncthreads();   // producer (all waves write all 16 tokens) -> consumer

    __fp16* resL = (__fp16*)qT;            // res overlay: row stride 520 halves

    // ---- consumer: each wave runs 4 tokens serially
    for (int i = 0; i < 4; ++i) {
        const int t = w * 4 + i;

        union { half8 h8; half2v h2[4]; } uq;
        uq.h8 = *(const half8*)&qT[t * TOKPAD + lane * 4];  // qT row t dead after this

        // dot row (pre-scaled by am1/8 via Wq): row[j] = sum_h q[h][lane]*k[h][j]
        float2v rowv[32];
        #pragma unroll
        for (int j = 0; j < 64; j += 2) {
            union { half8 h8; half2v h2[4]; } u0, u1;
            u0.h8 = *(const half8*)&kT[t * TOKPAD + j * 4];        // broadcast b128
            u1.h8 = *(const half8*)&kT[t * TOKPAD + (j + 1) * 4];
            float d0 = dot2(uq.h2[0], u0.h2[0], 0.0f);
            float d1 = dot2(uq.h2[0], u1.h2[0], 0.0f);
            d0 = dot2(uq.h2[1], u0.h2[1], d0);
            d1 = dot2(uq.h2[1], u1.h2[1], d1);
            d0 = dot2(uq.h2[2], u0.h2[2], d0);
            d1 = dot2(uq.h2[2], u1.h2[2], d1);
            d0 = dot2(uq.h2[3], u0.h2[3], d0);
            d1 = dot2(uq.h2[3], u1.h2[3], d1);
            rowv[j >> 1] = (float2v){d0, d1};
        }

        // max over 64 (4-way ILP)
        float m0 = fmaxf(rowv[0].x, rowv[0].y);
        float m1 = fmaxf(rowv[1].x, rowv[1].y);
        float m2 = fmaxf(rowv[2].x, rowv[2].y);
        float m3 = fmaxf(rowv[3].x, rowv[3].y);
        #pragma unroll
        for (int jj = 4; jj < 32; jj += 4) {
            m0 = fmaxf(m0, fmaxf(rowv[jj + 0].x, rowv[jj + 0].y));
            m1 = fmaxf(m1, fmaxf(rowv[jj + 1].x, rowv[jj + 1].y));
            m2 = fmaxf(m2, fmaxf(rowv[jj + 2].x, rowv[jj + 2].y));
            m3 = fmaxf(m3, fmaxf(rowv[jj + 3].x, rowv[jj + 3].y));
        }
        const float mx = fmaxf(fmaxf(m0, m1), fmaxf(m2, m3));

        float tau_lo = mx - 1.0f;                         // _gp(1, alpha) = 1
        const float tau_hi = mx - exp2f(-6.0f * am1);     // (1/64)^am1
        float dm = tau_hi - tau_lo;
        float inv_sum;
        half2v p2[32];

        if (am1 == 0.5f) {
            // NOTE: upper clamp of old clamp01 is dead here: tau >= mx-1
            // always, so z = row - tau <= 1. max(z,0) is exact.
            // 6 bisection steps, f >= 0 test (f_lo >= 0 provably)
            #pragma unroll
            for (int it = 0; it < 6; ++it) {
                dm *= 0.5f;
                const float tau_m = tau_lo + dm;
                const float2v nt = {-tau_m, -tau_m};
                float2v f0 = {-1.0f, 0.0f}, f1 = {0.0f, 0.0f},
                        f2 = {0.0f, 0.0f}, f3 = {0.0f, 0.0f};
                #pragma unroll
                for (int jj = 0; jj < 32; jj += 4) {
                    float2v a0 = pk_add(rowv[jj + 0], nt);
                    float2v a1 = pk_add(rowv[jj + 1], nt);
                    float2v a2 = pk_add(rowv[jj + 2], nt);
                    float2v a3 = pk_add(rowv[jj + 3], nt);
                    a0.x = fmaxf(a0.x, 0.0f); a0.y = fmaxf(a0.y, 0.0f);
                    a1.x = fmaxf(a1.x, 0.0f); a1.y = fmaxf(a1.y, 0.0f);
                    a2.x = fmaxf(a2.x, 0.0f); a2.y = fmaxf(a2.y, 0.0f);
                    a3.x = fmaxf(a3.x, 0.0f); a3.y = fmaxf(a3.y, 0.0f);
                    f0 = pk_fma(a0, a0, f0);
                    f1 = pk_fma(a1, a1, f1);
                    f2 = pk_fma(a2, a2, f2);
                    f3 = pk_fma(a3, a3, f3);
                }
                const float2v ft = pk_add(pk_add(f0, f1), pk_add(f2, f3));
                const float f = ft.x + ft.y;
                tau_lo = (f >= 0.0f) ? tau_m : tau_lo;
            }
            // 2 guarded Newton steps (tau += max(f,0)/(2s); never moves if f<0)
            float tau = tau_lo;
            #pragma unroll
            for (int it = 0; it < 2; ++it) {
                const float2v nt = {-tau, -tau};
                float2v f0 = {-1.0f, 0.0f}, f1 = {0.0f, 0.0f};
                float2v s0 = {0.0f, 0.0f}, s1 = {0.0f, 0.0f};
                #pragma unroll
                for (int jj = 0; jj < 32; jj += 2) {
                    float2v a0 = pk_add(rowv[jj + 0], nt);
                    float2v a1 = pk_add(rowv[jj + 1], nt);
                    a0.x = fmaxf(a0.x, 0.0f); a0.y = fmaxf(a0.y, 0.0f);
                    a1.x = fmaxf(a1.x, 0.0f); a1.y = fmaxf(a1.y, 0.0f);
                    f0 = pk_fma(a0, a0, f0);
                    f1 = pk_fma(a1, a1, f1);
                    s0 = pk_add(s0, a0);
                    s1 = pk_add(s1, a1);
                }
                const float2v ft = pk_add(f0, f1);
                const float2v st = pk_add(s0, s1);
                const float f = ft.x + ft.y;
                const float s = (st.x + st.y) + 1e-20f;   // s >= 1/8 at root
                tau = tau + fmaxf(f, 0.0f) * __builtin_amdgcn_rcpf(s + s);
            }
            // final p (unnormalized) + sum; normalization folded into av
            const float2v nt = {-tau, -tau};
            float2v sa = {0.0f, 0.0f}, sb = {0.0f, 0.0f};
            #pragma unroll
            for (int jj = 0; jj < 32; jj += 2) {
                float2v a0 = pk_add(rowv[jj + 0], nt);
                float2v a1 = pk_add(rowv[jj + 1], nt);
                a0.x = fmaxf(a0.x, 0.0f); a0.y = fmaxf(a0.y, 0.0f);
                a1.x = fmaxf(a1.x, 0.0f); a1.y = fmaxf(a1.y, 0.0f);
                const float2v q0 = pk_mul(a0, a0);
                const float2v q1 = pk_mul(a1, a1);
                sa = pk_add(sa, q0);
                sb = pk_add(sb, q1);
                p2[jj + 0] = pk(q0.x, q0.y);
                p2[jj + 1] = pk(q1.x, q1.y);
            }
            const float2v st = pk_add(sa, sb);
            inv_sum = 1.0f / (st.x + st.y);
        } else {
            // faithful general-alpha path (unused for this problem's alpha=1.5)
            const float inv = 1.0f / am1;
            float tau_m = tau_lo;
            float f_lo = -1.0f;
            #pragma unroll
            for (int jj = 0; jj < 32; ++jj) {
                f_lo += pgen(rowv[jj].x - tau_lo, inv);
                f_lo += pgen(rowv[jj].y - tau_lo, inv);
            }
            for (int it = 0; it < 30; ++it) {
                dm *= 0.5f;
                tau_m = tau_lo + dm;
                float f = -1.0f;
                #pragma unroll
                for (int jj = 0; jj < 32; ++jj) {
                    f += pgen(rowv[jj].x - tau_m, inv);
                    f += pgen(rowv[jj].y - tau_m, inv);
                }
                tau_lo = (f * f_lo >= 0.0f) ? tau_m : tau_lo;
            }
            float s = 0.0f;
            #pragma unroll
            for (int jj = 0; jj < 32; ++jj) {
                const float pa = pgen(rowv[jj].x - tau_m, inv);
                const float pb = pgen(rowv[jj].y - tau_m, inv);
                p2[jj] = pk(pa, pb);
                s += pa + pb;
            }
            inv_sum = 1.0f / s;
        }

        // av: res[h][lane] = inv_sum * sum_j p[j] * v[h][j]  via fp16 dot2
        float acc[8];
        #pragma unroll
        for (int h = 0; h < 8; ++h) {
            float a0 = 0.0f, a1 = 0.0f;
            #pragma unroll
            for (int jc = 0; jc < 8; ++jc) {
                union { half8 h8; half2v h2[4]; } u;
                u.h8 = *(const half8*)&vT[t * TOKPAD + h * 32 + jc * 4];
                a0 = dot2(p2[jc * 4 + 0], u.h2[0], a0);
                a1 = dot2(p2[jc * 4 + 1], u.h2[1], a1);
                a0 = dot2(p2[jc * 4 + 2], u.h2[2], a0);
                a1 = dot2(p2[jc * 4 + 3], u.h2[3], a1);
            }
            acc[h] = a0 + a1;
        }
        // res -> LDS overlay of qT row t (wave-private row; same fp16 cast
        // as before => identical values feed the out MFMA)
        #pragma unroll
        for (int h = 0; h < 8; ++h)
            resL[t * 520 + h * 64 + lane] = (__fp16)(acc[h] * inv_sum);
    }
    __syncthreads();   // all 16 tokens' res in LDS -> out phase

    // ---- out phase: wave w computes out cols w*16..w*16+15 for 16 tokens.
    {
        floatx4 oacc = (floatx4){0.f, 0.f, 0.f, 0.f};
        const __fp16* rrow = resL + (size_t)m * 520 + quad * 8;   // token m
        const __fp16* wrow = wuh + (size_t)(w * 16 + m) * HHE + quad * 8;
        #pragma unroll
        for (int kc = 0; kc < 16; ++kc) {              // K=512 in 32-chunks
            const half8 bf = *(const half8*)(rrow + kc * 32);
            const half8 af = *(const half8*)(wrow + kc * 32);
            oacc = __builtin_amdgcn_mfma_f32_16x16x32_f16(af, bf, oacc, 0, 0, 0);
        }
        const int tok = tok0 + m;
        const int col = w * 16 + quad * 4;             // 4 consecutive out cols
        const float4 b4 = *(const float4*)&bu[col];
        float4 o;
        o.x = oacc[0] + b4.x;
        o.y = oacc[1] + b4.y;
        o.z = oacc[2] + b4.z;
        o.w = oacc[3] + b4.w;
        *(float4*)&out[(size_t)tok * 64 + col] = o;
    }
}

// ---------------------------------------------------------------------------
extern "C" void kernel_launch(void* const* d_in, const int* in_sizes, int n_in,
                              void* d_out, int out_size, void* d_ws, size_t ws_size,
                              hipStream_t stream)
{
    const float* x     = (const float*)d_in[0];
    const float* alpha = (const float*)d_in[1];
    const float* Wk    = (const float*)d_in[2];
    const float* bk    = (const float*)d_in[3];
    const float* Wq    = (const float*)d_in[4];
    const float* bq    = (const float*)d_in[5];
    const float* Wv    = (const float*)d_in[6];
    const float* bv    = (const float*)d_in[7];
    const float* Wu    = (const float*)d_in[8];
    const float* bu    = (const float*)d_in[9];
    float* out = (float*)d_out;

    // workspace (fp16 units): wkh/wqh/wvh/wuh 32768 each
    __fp16* wkh  = (__fp16*)d_ws;
    __fp16* wqh  = wkh + (size_t)HHE * EDIM;
    __fp16* wvh  = wqh + (size_t)HHE * EDIM;
    __fp16* wuh  = wvh + (size_t)HHE * EDIM;

    cvt_fp16_kernel<<<dim3(16, 4), 256, 0, stream>>>(
        Wk, Wq, Wv, Wu, wkh, wqh, wvh, wuh, alpha);
    qkv_attn_out_kernel<<<NTOK / 16, 256, 0, stream>>>(
        x, wkh, bk, wqh, bq, wvh, bv, wuh, bu, out, alpha);
}